// Round 10
// baseline (489.109 us; speedup 1.0000x reference)
//
#include <hip/hip_runtime.h>

typedef __attribute__((ext_vector_type(8))) unsigned short us8;
typedef __attribute__((ext_vector_type(8))) short s8;
typedef __attribute__((ext_vector_type(4))) float f4;
typedef __attribute__((ext_vector_type(2))) float f2;

#define DEV static __device__ __forceinline__
#define CAP 128
#define NBB 256    // bucketing blocks
#define SEGC 1024  // per (range,block) segment capacity

DEV float bf2f(unsigned short h){ return __uint_as_float(((unsigned)h)<<16); }
DEV unsigned short f2bf(float f){
  unsigned x = __float_as_uint(f);
  x += 0x7fffu + ((x>>16)&1u);
  return (unsigned short)(x>>16);
}
DEV float sigm(float x){ return 1.f/(1.f + __expf(-x)); }

// ---------------- setup kernels ----------------
// Pass 1: partition edges into 8 dst-ranges, private per-(range,block) segments.
__global__ __launch_bounds__(256) void k_bucket(const int* __restrict__ src,
    const int* __restrict__ dst, unsigned* __restrict__ buf,
    int* __restrict__ cnt2, int e, int n){
  __shared__ int lcnt[8];
  int b = blockIdx.x;
  if(threadIdx.x < 8) lcnt[threadIdx.x] = 0;
  __syncthreads();
  int chunk = (e + NBB - 1)/NBB;
  int lo = b*chunk;
  int hi = lo + chunk; if(hi>e) hi=e;
  float scale = 8.0f/(float)n;
  for(int i = lo + threadIdx.x; i < hi; i += 256){
    int d = dst[i], s = src[i];
    int r = (int)((float)d*scale); r = r>7?7:r;
    int pos = atomicAdd(&lcnt[r], 1);
    if(pos < SEGC)
      buf[((size_t)r*NBB + b)*SEGC + pos] = ((unsigned)d<<16) | (unsigned)s;
  }
  __syncthreads();
  if(threadIdx.x < 8) cnt2[threadIdx.x*NBB + b] = lcnt[threadIdx.x];
}

// Pass 2: each XCD-range group drains its segments; col window is L2-local.
__global__ __launch_bounds__(256) void k_build2(const unsigned* __restrict__ buf,
    const int* __restrict__ cnt2, int* __restrict__ cnt,
    unsigned short* __restrict__ col){
  int r = blockIdx.x & 7;
  int nb = gridDim.x >> 3;
  int j = blockIdx.x >> 3;
  for(int seg = j; seg < NBB; seg += nb){
    int c = cnt2[r*NBB + seg]; if(c > SEGC) c = SEGC;
    const unsigned* p = buf + ((size_t)r*NBB + seg)*SEGC;
    for(int i = threadIdx.x; i < c; i += 256){
      unsigned v = p[i];
      int d = (int)(v >> 16), s = (int)(v & 0xffffu);
      int slot = atomicAdd(&cnt[d], 1);
      col[(size_t)d*CAP + slot] = (unsigned short)s;
    }
  }
}

// dinv (blocks [0,gN)) + weight transpose/bf16 (blocks [gN, gN+768))
__global__ void k_setup(const int* __restrict__ cnt, float* __restrict__ dinv, int n,
                        const float* __restrict__ Wx, const float* __restrict__ Wh,
                        unsigned short* __restrict__ WT){
  int gN = (n + 255)/256;
  int b = blockIdx.x;
  if(b < gN){
    int i = b*256 + threadIdx.x;
    if(i<n) dinv[i] = rsqrtf((float)cnt[i] + 1.0f);
  } else {
    int i = (b-gN)*256 + threadIdx.x;   // < 12*16384
    int m = i >> 14;
    int rem = i & 16383;
    int j = rem >> 7;     // output column
    int k = rem & 127;    // k index
    const float* W = (m<6) ? (Wx + (size_t)m*16384) : (Wh + (size_t)(m-6)*16384);
    WT[(size_t)m*16384 + rem] = f2bf(W[(size_t)k*128 + j]);
  }
}

// ---------------- per-layer kernels ----------------
// FULL=1: y2[n,0:128]=fp8(dinv*inp), y2[n,128:256]=fp8(dinv*hl)
// FULL=0: only the h-half (x-half was written by previous layer's MODE2)
template<int FULL>
__global__ void k_scale2(const float* __restrict__ inp, const float* __restrict__ hl,
                         const float* __restrict__ dinv, unsigned char* __restrict__ y2, int n){
  int i = blockIdx.x*blockDim.x+threadIdx.x;
  if(i >= n*32) return;
  int node = i>>5, d0 = (i&31)*4;
  float dv = dinv[node];
  f4 b = *(const f4*)(hl  + (size_t)node*128 + d0);
  unsigned pb = __builtin_amdgcn_cvt_pk_fp8_f32(dv*b[0], dv*b[1], 0, false);
  pb = __builtin_amdgcn_cvt_pk_fp8_f32(dv*b[2], dv*b[3], pb, true);
  *(unsigned*)(y2 + (size_t)node*256 + 128 + d0) = pb;
  if constexpr(FULL){
    f4 a = *(const f4*)(inp + (size_t)node*128 + d0);
    unsigned pa = __builtin_amdgcn_cvt_pk_fp8_f32(dv*a[0], dv*a[1], 0, false);
    pa = __builtin_amdgcn_cvt_pk_fp8_f32(dv*a[2], dv*a[3], pa, true);
    *(unsigned*)(y2 + (size_t)node*256 + d0) = pa;
  }
}

// CSR aggregation over fp8 rows: out_bf16 = dinv[n] * ( y[n] + sum y[src] )
// DB = row bytes (256 -> ax|ah, 128 -> aq). 16B per lane.
template<int DB>
__global__ __launch_bounds__(256) void k_agg(const unsigned char* __restrict__ y,
    const int* __restrict__ cnt, const unsigned short* __restrict__ col,
    const float* __restrict__ dinv, unsigned short* __restrict__ out0,
    unsigned short* __restrict__ out1, int n)
{
  constexpr int GL = DB/16;      // lanes per node
  constexpr int NG = 64/GL;      // nodes per wave
  constexpr int U = 8;
  int tid = threadIdx.x;
  int wave = tid>>6, lane = tid&63;
  int g = lane/GL, gl = lane%GL;
  int node = blockIdx.x*(4*NG) + wave*NG + g;
  if(node >= n) return;
  const unsigned char* yb = y + (size_t)gl*16;
  float acc[16];
  {
    uint4 q = *(const uint4*)(yb + (size_t)node*DB);
    const unsigned* qw = (const unsigned*)&q;
    #pragma unroll
    for(int w=0;w<4;++w){
      f2 lo = __builtin_amdgcn_cvt_pk_f32_fp8(qw[w], false);
      f2 hi = __builtin_amdgcn_cvt_pk_f32_fp8(qw[w], true);
      acc[w*4+0]=lo[0]; acc[w*4+1]=lo[1]; acc[w*4+2]=hi[0]; acc[w*4+3]=hi[1];
    }
  }
  const unsigned short* myrow = col + (size_t)node*CAP;
  int c_ = cnt[node];
  int last = c_ - 1;
  for(int i=0; i<c_; i += U){
    int s[U];
    #pragma unroll
    for(int u=0;u<U;++u){
      int ii = i + u; ii = (ii < last) ? ii : last;
      s[u] = myrow[ii];
    }
    uint4 v[U];
    #pragma unroll
    for(int u=0;u<U;++u) v[u] = *(const uint4*)(yb + (size_t)s[u]*DB);
    #pragma unroll
    for(int u=0;u<U;++u){
      if(i + u < c_){
        const unsigned* qw = (const unsigned*)&v[u];
        #pragma unroll
        for(int w=0;w<4;++w){
          f2 lo = __builtin_amdgcn_cvt_pk_f32_fp8(qw[w], false);
          f2 hi = __builtin_amdgcn_cvt_pk_f32_fp8(qw[w], true);
          acc[w*4+0]+=lo[0]; acc[w*4+1]+=lo[1]; acc[w*4+2]+=hi[0]; acc[w*4+3]+=hi[1];
        }
      }
    }
  }
  float dv = dinv[node];
  us8 w0, w1;
  #pragma unroll
  for(int j=0;j<8;++j){ w0[j]=f2bf(acc[j]*dv); w1[j]=f2bf(acc[8+j]*dv); }
  int c = gl*16;
  if constexpr(DB==128){
    *(us8*)(out0 + (size_t)node*128 + c)     = w0;
    *(us8*)(out0 + (size_t)node*128 + c + 8) = w1;
  } else {
    unsigned short* o = (c<128) ? (out0 + (size_t)node*128 + c)
                                : (out1 + (size_t)node*128 + (c-128));
    *(us8*)o = w0;
    *(us8*)(o+8) = w1;
  }
}

// ---- shared GEMM helpers ----
DEV void stageA(unsigned short* As, const unsigned short* A, int brow, int nrows, int t){
  #pragma unroll
  for(int i=0;i<8;++i){
    int c = t + i*256;
    int r = c >> 4, k0 = (c & 15)*8;
    us8 va = (us8)0;
    int gr = brow + r;
    if (gr < nrows) va = *(const us8*)(A + (size_t)gr*128 + k0);
    *(us8*)(&As[r*136 + k0]) = va;
  }
}
DEV void stageB(unsigned short* Bs, const unsigned short* B, int t){
  #pragma unroll
  for(int i=0;i<8;++i){
    int c = t + i*256;
    int r = c >> 4, k0 = (c & 15)*8;
    *(us8*)(&Bs[r*136 + k0]) = *(const us8*)(B + (size_t)c*8);
  }
}
DEV void mfma16(const unsigned short* As, const unsigned short* Bs,
                f4 (&acc)[4][4], int wr, int wc, int lo, int hi){
  #pragma unroll
  for(int kk=0;kk<4;++kk){
    s8 af[4], bfr[4];
    #pragma unroll
    for(int m=0;m<4;++m)
      af[m] = *(const s8*)(&As[(wr*64 + m*16 + lo)*136 + kk*32 + hi*8]);
    #pragma unroll
    for(int n=0;n<4;++n)
      bfr[n] = *(const s8*)(&Bs[(wc*64 + n*16 + lo)*136 + kk*32 + hi*8]);
    #pragma unroll
    for(int m=0;m<4;++m)
      #pragma unroll
      for(int n=0;n<4;++n)
        acc[m][n] = __builtin_amdgcn_mfma_f32_16x16x32_bf16(af[m], bfr[n], acc[m][n], 0,0,0);
  }
}

// Fused first-stage: Zb[:,0:128]=bf16(ax@Wxz+ah@Whz), Zb[:,128:256]=bf16(ax@Wxh)
__global__ __launch_bounds__(256) void k_gemmZH(const unsigned short* __restrict__ ax,
    const unsigned short* __restrict__ ah, const unsigned short* __restrict__ Wxz,
    const unsigned short* __restrict__ Whz, const unsigned short* __restrict__ Wxh,
    unsigned short* __restrict__ Zb, int nrows)
{
  __shared__ unsigned short As[128*136];
  __shared__ unsigned short Bs[128*136];
  const int t = threadIdx.x;
  const int lane = t & 63;
  const int lo = lane & 15, hi = lane >> 4;
  const int wid = t >> 6;
  const int wr = wid >> 1, wc = wid & 1;
  const int brow = blockIdx.x * 128;
  f4 accZ[4][4], accH[4][4];
  #pragma unroll
  for(int m=0;m<4;++m)
    #pragma unroll
    for(int n=0;n<4;++n){ accZ[m][n] = (f4)0.f; accH[m][n] = (f4)0.f; }

  stageA(As, ax, brow, nrows, t);
  stageB(Bs, Wxz, t);
  __syncthreads();
  mfma16(As, Bs, accZ, wr, wc, lo, hi);
  __syncthreads();
  stageB(Bs, Wxh, t);
  __syncthreads();
  mfma16(As, Bs, accH, wr, wc, lo, hi);
  __syncthreads();
  stageA(As, ah, brow, nrows, t);
  stageB(Bs, Whz, t);
  __syncthreads();
  mfma16(As, Bs, accZ, wr, wc, lo, hi);

  const int c0 = wc*64;
  #pragma unroll
  for(int n=0;n<4;++n){
    const int colv = c0 + n*16 + lo;
    #pragma unroll
    for(int m=0;m<4;++m){
      int rbase = brow + wr*64 + m*16 + hi*4;
      #pragma unroll
      for(int tt=0;tt<4;++tt){
        int row = rbase + tt;
        if(row >= nrows) continue;
        Zb[(size_t)row*256 + colv]       = f2bf(accZ[m][n][tt]);
        Zb[(size_t)row*256 + 128 + colv] = f2bf(accH[m][n][tt]);
      }
    }
  }
}

// MODE 1: yq[row*128+col] = fp8( dinv*sigm(acc + b1+b2) * hl )
// MODE 2: z = sigm(bf2f(Zb[row*256+col]) + b1+b2);
//         ht = tanh(acc + bf2f(Zb[row*256+128+col]) + b3+b4)
//         outp = z*hl + (1-z)*ht;  optional y2out[row*256+col] = fp8(dinv*outp)
template<int MODE>
__global__ __launch_bounds__(256) void k_gemm(const unsigned short* __restrict__ A1,
    const unsigned short* __restrict__ A2, const unsigned short* __restrict__ B1,
    const unsigned short* __restrict__ B2, const unsigned short* __restrict__ Zb,
    const float* __restrict__ hl, const float* __restrict__ dinv,
    const float* __restrict__ b1, const float* __restrict__ b2,
    const float* __restrict__ b3, const float* __restrict__ b4,
    unsigned char* __restrict__ yq, float* __restrict__ outp,
    unsigned char* __restrict__ y2out, int nrows)
{
  __shared__ unsigned short As[128*136];
  __shared__ unsigned short Bs[128*136];
  const int t = threadIdx.x;
  const int lane = t & 63;
  const int lo = lane & 15, hi = lane >> 4;
  const int wid = t >> 6;
  const int wr = wid >> 1, wc = wid & 1;
  const int brow = blockIdx.x * 128;
  f4 acc[4][4];
  #pragma unroll
  for(int m=0;m<4;++m)
    #pragma unroll
    for(int n=0;n<4;++n) acc[m][n] = (f4)0.f;

  const int nch = A2 ? 2 : 1;
  for(int ch=0; ch<nch; ++ch){
    __syncthreads();
    stageA(As, ch ? A2 : A1, brow, nrows, t);
    stageB(Bs, ch ? B2 : B1, t);
    __syncthreads();
    mfma16(As, Bs, acc, wr, wc, lo, hi);
  }

  const int c0 = wc*64;
  #pragma unroll
  for(int n=0;n<4;++n){
    const int colv = c0 + n*16 + lo;
    float bz = b1[colv] + b2[colv];
    float bh = 0.f;
    if constexpr(MODE==2){ bh = b3[colv] + b4[colv]; }
    #pragma unroll
    for(int m=0;m<4;++m){
      int rbase = brow + wr*64 + m*16 + hi*4;
      #pragma unroll
      for(int tt=0;tt<4;++tt){
        int row = rbase + tt;
        if(row >= nrows) continue;
        float v = acc[m][n][tt];
        if constexpr(MODE==1){
          float r = sigm(v + bz);
          float q = dinv[row] * r * hl[(size_t)row*128 + colv];
          unsigned pk = __builtin_amdgcn_cvt_pk_fp8_f32(q, q, 0, false);
          yq[(size_t)row*128 + colv] = (unsigned char)(pk & 0xff);
        } else {
          float z  = sigm(bf2f(Zb[(size_t)row*256 + colv]) + bz);
          float ht = tanhf(v + bf2f(Zb[(size_t)row*256 + 128 + colv]) + bh);
          float ov = z*hl[(size_t)row*128 + colv] + (1.f - z)*ht;
          outp[(size_t)row*128 + colv] = ov;
          if(y2out){
            float q = dinv[row] * ov;
            unsigned pk = __builtin_amdgcn_cvt_pk_fp8_f32(q, q, 0, false);
            y2out[(size_t)row*256 + colv] = (unsigned char)(pk & 0xff);
          }
        }
      }
    }
  }
}

extern "C" void kernel_launch(void* const* d_in, const int* in_sizes, int n_in,
                              void* d_out, int out_size, void* d_ws, size_t ws_size,
                              hipStream_t stream){
  const float* x  = (const float*)d_in[0];
  const int*   ei = (const int*)d_in[1];
  const float* h  = (const float*)d_in[2];
  const float* Wx = (const float*)d_in[3];
  const float* bx = (const float*)d_in[4];
  const float* Wh = (const float*)d_in[5];
  const float* bh = (const float*)d_in[6];
  float* out = (float*)d_out;

  const int N = in_sizes[0] / 128;
  const int E = in_sizes[1] / 2;
  const int L = in_sizes[2] / in_sizes[0];
  const int* src = ei;
  const int* dst = ei + E;

  char* w = (char*)d_ws;
  auto alloc = [&](size_t b)->char*{ char* p = w; w += (b + 255) & ~(size_t)255; return p; };
  int* cnt = (int*)alloc((size_t)N*sizeof(int));
  unsigned short* col = (unsigned short*)alloc((size_t)N*CAP*sizeof(short));
  float* dinv = (float*)alloc((size_t)N*sizeof(float));
  unsigned short* WT = (unsigned short*)alloc((size_t)12*16384*sizeof(short));
  unsigned char* y2 = (unsigned char*)alloc((size_t)N*256);
  unsigned short* ax = (unsigned short*)alloc((size_t)N*128*sizeof(short));
  unsigned short* ah = (unsigned short*)alloc((size_t)N*128*sizeof(short));
  unsigned char* yq = (unsigned char*)alloc((size_t)N*128);
  unsigned short* aq = (unsigned short*)alloc((size_t)N*128*sizeof(short));
  unsigned short* Zb = (unsigned short*)alloc((size_t)N*256*sizeof(short));
  unsigned* ebuf = (unsigned*)alloc((size_t)8*NBB*SEGC*sizeof(unsigned));
  int* cnt2 = (int*)alloc((size_t)8*NBB*sizeof(int));

  const int gN = (N + 255)/256;
  const int gew = (N*32 + 255)/256;
  const int grows = (N + 127)/128;
  const int gagg4 = (N + 15)/16;   // DB=256: 16 nodes/block
  const int gagg2 = (N + 31)/32;   // DB=128: 32 nodes/block

  hipMemsetAsync(cnt, 0, (size_t)N*sizeof(int), stream);
  k_bucket<<<NBB,256,0,stream>>>(src, dst, ebuf, cnt2, E, N);
  k_build2<<<8*32,256,0,stream>>>(ebuf, cnt2, cnt, col);
  k_setup<<<gN + 768,256,0,stream>>>(cnt, dinv, N, Wx, Wh, WT);

  for(int l=0; l<L; ++l){
    const float* inp = (l==0) ? x : (out + (size_t)(l-1)*N*128);
    const float* hl  = h + (size_t)l*N*128;
    const float* bxz = bx + (size_t)(l*3+0)*128; const float* bhz = bh + (size_t)(l*3+0)*128;
    const float* bxr = bx + (size_t)(l*3+1)*128; const float* bhr = bh + (size_t)(l*3+1)*128;
    const float* bxh = bx + (size_t)(l*3+2)*128; const float* bhh = bh + (size_t)(l*3+2)*128;
    const unsigned short* Wxz = WT + (size_t)(l*3+0)*16384;
    const unsigned short* Wxr = WT + (size_t)(l*3+1)*16384;
    const unsigned short* Wxh = WT + (size_t)(l*3+2)*16384;
    const unsigned short* Whz = WT + (size_t)(6+l*3+0)*16384;
    const unsigned short* Whr = WT + (size_t)(6+l*3+1)*16384;
    const unsigned short* Whh = WT + (size_t)(6+l*3+2)*16384;

    if(l==0) k_scale2<1><<<gew,256,0,stream>>>(inp, hl, dinv, y2, N);
    else     k_scale2<0><<<gew,256,0,stream>>>(inp, hl, dinv, y2, N);
    k_agg<256><<<gagg4,256,0,stream>>>(y2, cnt, col, dinv, ax, ah, N);
    // fused z-pre + ht-partial
    k_gemmZH<<<grows,256,0,stream>>>(ax, ah, Wxz, Whz, Wxh, Zb, N);
    // r fused: yq = fp8(dinv * sigm(ax@Wxr + ah@Whr + bxr+bhr) * h)
    k_gemm<1><<<grows,256,0,stream>>>(ax, ah, Wxr, Whr, nullptr,
                                      hl, dinv, bxr, bhr, nullptr, nullptr,
                                      yq, nullptr, nullptr, N);
    k_agg<128><<<gagg2,256,0,stream>>>(yq, cnt, col, dinv, aq, nullptr, N);
    // final fused: out = z*h + (1-z)*tanh(aq@Whh + Zb[:,128:256] + bxh+bhh)
    // also emit next layer's y2 x-half = fp8(dinv*out)
    k_gemm<2><<<grows,256,0,stream>>>(aq, nullptr, Whh, nullptr, Zb,
                                      hl, dinv, bxz, bhz, bxh, bhh,
                                      nullptr, out + (size_t)l*N*128,
                                      (l+1<L) ? y2 : nullptr, N);
  }
}

// Round 11
// 453.429 us; speedup vs baseline: 1.0787x; 1.0787x over previous
//
#include <hip/hip_runtime.h>

typedef __attribute__((ext_vector_type(8))) unsigned short us8;
typedef __attribute__((ext_vector_type(8))) short s8;
typedef __attribute__((ext_vector_type(4))) float f4;
typedef __attribute__((ext_vector_type(2))) float f2;

#define DEV static __device__ __forceinline__
#define CAP 128
#define NRG 128    // dst ranges (one pass-2 block per range)
#define NBB 256    // bucketing blocks
#define SEGC 128   // per (range,block) segment capacity

DEV float bf2f(unsigned short h){ return __uint_as_float(((unsigned)h)<<16); }
DEV unsigned short f2bf(float f){
  unsigned x = __float_as_uint(f);
  x += 0x7fffu + ((x>>16)&1u);
  return (unsigned short)(x>>16);
}
DEV float sigm(float x){ return 1.f/(1.f + __expf(-x)); }

// ---------------- setup kernels ----------------
// Pass 1: partition edges into NRG dst-ranges, private per-(range,block)
// segments; only LDS atomics.
__global__ __launch_bounds__(256) void k_bucket(const int* __restrict__ src,
    const int* __restrict__ dst, unsigned* __restrict__ buf,
    int* __restrict__ cnt2, int e, int n){
  __shared__ int lcnt[NRG];
  int b = blockIdx.x;
  for(int i=threadIdx.x;i<NRG;i+=256) lcnt[i] = 0;
  __syncthreads();
  int chunk = (e + NBB - 1)/NBB;
  int lo = b*chunk;
  int hi = lo + chunk; if(hi>e) hi=e;
  for(int i = lo + threadIdx.x; i < hi; i += 256){
    int d = dst[i], s = src[i];
    int r = (d*NRG)/n;
    int pos = atomicAdd(&lcnt[r], 1);
    if(pos < SEGC)
      buf[((size_t)r*NBB + b)*SEGC + pos] = ((unsigned)d<<16) | (unsigned)s;
  }
  __syncthreads();
  for(int i=threadIdx.x;i<NRG;i+=256) cnt2[i*NBB + b] = lcnt[i];
}

// Pass 2: one block per range; per-range cnt lives in LDS (no global atomics).
__global__ __launch_bounds__(256) void k_build2(const unsigned* __restrict__ buf,
    const int* __restrict__ cnt2, int* __restrict__ cnt,
    unsigned short* __restrict__ col, int n){
  int r = blockIdx.x;
  int lo = (r*n + NRG-1)/NRG;
  int hi = ((r+1)*n + NRG-1)/NRG;   // exclusive
  int span = hi - lo;
  __shared__ int lc[512];
  for(int i=threadIdx.x; i<span; i+=256) lc[i] = 0;
  __syncthreads();
  int lane = threadIdx.x & 63;
  for(int seg = threadIdx.x>>6; seg < NBB; seg += 4){
    int c = cnt2[r*NBB + seg]; if(c > SEGC) c = SEGC;
    const unsigned* p = buf + ((size_t)r*NBB + seg)*SEGC;
    for(int i = lane; i < c; i += 64){
      unsigned v = p[i];
      int d = (int)(v >> 16), s = (int)(v & 0xffffu);
      int slot = atomicAdd(&lc[d - lo], 1);
      col[(size_t)d*CAP + slot] = (unsigned short)s;
    }
  }
  __syncthreads();
  for(int i=threadIdx.x; i<span; i+=256) cnt[lo + i] = lc[i];
}

// dinv (blocks [0,gN)) + weight transpose/bf16 (blocks [gN, gN+768))
__global__ void k_setup(const int* __restrict__ cnt, float* __restrict__ dinv, int n,
                        const float* __restrict__ Wx, const float* __restrict__ Wh,
                        unsigned short* __restrict__ WT){
  int gN = (n + 255)/256;
  int b = blockIdx.x;
  if(b < gN){
    int i = b*256 + threadIdx.x;
    if(i<n) dinv[i] = rsqrtf((float)cnt[i] + 1.0f);
  } else {
    int i = (b-gN)*256 + threadIdx.x;   // < 12*16384
    int m = i >> 14;
    int rem = i & 16383;
    int j = rem >> 7;     // output column
    int k = rem & 127;    // k index
    const float* W = (m<6) ? (Wx + (size_t)m*16384) : (Wh + (size_t)(m-6)*16384);
    WT[(size_t)m*16384 + rem] = f2bf(W[(size_t)k*128 + j]);
  }
}

// ---------------- per-layer kernels ----------------
// FULL=1: y2[n,0:128]=fp8(dinv*inp), y2[n,128:256]=fp8(dinv*hl)
// FULL=0: only the h-half (x-half was written by previous layer's MODE2)
template<int FULL>
__global__ void k_scale2(const float* __restrict__ inp, const float* __restrict__ hl,
                         const float* __restrict__ dinv, unsigned char* __restrict__ y2, int n){
  int i = blockIdx.x*blockDim.x+threadIdx.x;
  if(i >= n*32) return;
  int node = i>>5, d0 = (i&31)*4;
  float dv = dinv[node];
  f4 b = *(const f4*)(hl  + (size_t)node*128 + d0);
  unsigned pb = __builtin_amdgcn_cvt_pk_fp8_f32(dv*b[0], dv*b[1], 0, false);
  pb = __builtin_amdgcn_cvt_pk_fp8_f32(dv*b[2], dv*b[3], pb, true);
  *(unsigned*)(y2 + (size_t)node*256 + 128 + d0) = pb;
  if constexpr(FULL){
    f4 a = *(const f4*)(inp + (size_t)node*128 + d0);
    unsigned pa = __builtin_amdgcn_cvt_pk_fp8_f32(dv*a[0], dv*a[1], 0, false);
    pa = __builtin_amdgcn_cvt_pk_fp8_f32(dv*a[2], dv*a[3], pa, true);
    *(unsigned*)(y2 + (size_t)node*256 + d0) = pa;
  }
}

// CSR aggregation over fp8 rows: out_bf16 = dinv[n] * ( y[n] + sum y[src] )
// DB = row bytes (256 -> ax|ah, 128 -> aq). 16B per lane.
template<int DB>
__global__ __launch_bounds__(256) void k_agg(const unsigned char* __restrict__ y,
    const int* __restrict__ cnt, const unsigned short* __restrict__ col,
    const float* __restrict__ dinv, unsigned short* __restrict__ out0,
    unsigned short* __restrict__ out1, int n)
{
  constexpr int GL = DB/16;      // lanes per node
  constexpr int NG = 64/GL;      // nodes per wave
  constexpr int U = 8;
  int tid = threadIdx.x;
  int wave = tid>>6, lane = tid&63;
  int g = lane/GL, gl = lane%GL;
  int node = blockIdx.x*(4*NG) + wave*NG + g;
  if(node >= n) return;
  const unsigned char* yb = y + (size_t)gl*16;
  float acc[16];
  {
    uint4 q = *(const uint4*)(yb + (size_t)node*DB);
    const unsigned* qw = (const unsigned*)&q;
    #pragma unroll
    for(int w=0;w<4;++w){
      f2 lo = __builtin_amdgcn_cvt_pk_f32_fp8(qw[w], false);
      f2 hi = __builtin_amdgcn_cvt_pk_f32_fp8(qw[w], true);
      acc[w*4+0]=lo[0]; acc[w*4+1]=lo[1]; acc[w*4+2]=hi[0]; acc[w*4+3]=hi[1];
    }
  }
  const unsigned short* myrow = col + (size_t)node*CAP;
  int c_ = cnt[node];
  int last = c_ - 1;
  for(int i=0; i<c_; i += U){
    int s[U];
    #pragma unroll
    for(int u=0;u<U;++u){
      int ii = i + u; ii = (ii < last) ? ii : last;
      s[u] = myrow[ii];
    }
    uint4 v[U];
    #pragma unroll
    for(int u=0;u<U;++u) v[u] = *(const uint4*)(yb + (size_t)s[u]*DB);
    #pragma unroll
    for(int u=0;u<U;++u){
      if(i + u < c_){
        const unsigned* qw = (const unsigned*)&v[u];
        #pragma unroll
        for(int w=0;w<4;++w){
          f2 lo = __builtin_amdgcn_cvt_pk_f32_fp8(qw[w], false);
          f2 hi = __builtin_amdgcn_cvt_pk_f32_fp8(qw[w], true);
          acc[w*4+0]+=lo[0]; acc[w*4+1]+=lo[1]; acc[w*4+2]+=hi[0]; acc[w*4+3]+=hi[1];
        }
      }
    }
  }
  float dv = dinv[node];
  us8 w0, w1;
  #pragma unroll
  for(int j=0;j<8;++j){ w0[j]=f2bf(acc[j]*dv); w1[j]=f2bf(acc[8+j]*dv); }
  int c = gl*16;
  if constexpr(DB==128){
    *(us8*)(out0 + (size_t)node*128 + c)     = w0;
    *(us8*)(out0 + (size_t)node*128 + c + 8) = w1;
  } else {
    unsigned short* o = (c<128) ? (out0 + (size_t)node*128 + c)
                                : (out1 + (size_t)node*128 + (c-128));
    *(us8*)o = w0;
    *(us8*)(o+8) = w1;
  }
}

// ---- shared GEMM helpers ----
DEV void stageA(unsigned short* As, const unsigned short* A, int brow, int nrows, int t){
  #pragma unroll
  for(int i=0;i<8;++i){
    int c = t + i*256;
    int r = c >> 4, k0 = (c & 15)*8;
    us8 va = (us8)0;
    int gr = brow + r;
    if (gr < nrows) va = *(const us8*)(A + (size_t)gr*128 + k0);
    *(us8*)(&As[r*136 + k0]) = va;
  }
}
DEV void stageB(unsigned short* Bs, const unsigned short* B, int t){
  #pragma unroll
  for(int i=0;i<8;++i){
    int c = t + i*256;
    int r = c >> 4, k0 = (c & 15)*8;
    *(us8*)(&Bs[r*136 + k0]) = *(const us8*)(B + (size_t)c*8);
  }
}
DEV void mfma16(const unsigned short* As, const unsigned short* Bs,
                f4 (&acc)[4][4], int wr, int wc, int lo, int hi){
  #pragma unroll
  for(int kk=0;kk<4;++kk){
    s8 af[4], bfr[4];
    #pragma unroll
    for(int m=0;m<4;++m)
      af[m] = *(const s8*)(&As[(wr*64 + m*16 + lo)*136 + kk*32 + hi*8]);
    #pragma unroll
    for(int n=0;n<4;++n)
      bfr[n] = *(const s8*)(&Bs[(wc*64 + n*16 + lo)*136 + kk*32 + hi*8]);
    #pragma unroll
    for(int m=0;m<4;++m)
      #pragma unroll
      for(int n=0;n<4;++n)
        acc[m][n] = __builtin_amdgcn_mfma_f32_16x16x32_bf16(af[m], bfr[n], acc[m][n], 0,0,0);
  }
}

// Fused first-stage: Zb[:,0:128]=bf16(ax@Wxz+ah@Whz), Zb[:,128:256]=bf16(ax@Wxh)
__global__ __launch_bounds__(256) void k_gemmZH(const unsigned short* __restrict__ ax,
    const unsigned short* __restrict__ ah, const unsigned short* __restrict__ Wxz,
    const unsigned short* __restrict__ Whz, const unsigned short* __restrict__ Wxh,
    unsigned short* __restrict__ Zb, int nrows)
{
  __shared__ unsigned short As[128*136];
  __shared__ unsigned short Bs[128*136];
  const int t = threadIdx.x;
  const int lane = t & 63;
  const int lo = lane & 15, hi = lane >> 4;
  const int wid = t >> 6;
  const int wr = wid >> 1, wc = wid & 1;
  const int brow = blockIdx.x * 128;
  f4 accZ[4][4], accH[4][4];
  #pragma unroll
  for(int m=0;m<4;++m)
    #pragma unroll
    for(int n=0;n<4;++n){ accZ[m][n] = (f4)0.f; accH[m][n] = (f4)0.f; }

  stageA(As, ax, brow, nrows, t);
  stageB(Bs, Wxz, t);
  __syncthreads();
  mfma16(As, Bs, accZ, wr, wc, lo, hi);
  __syncthreads();
  stageB(Bs, Wxh, t);
  __syncthreads();
  mfma16(As, Bs, accH, wr, wc, lo, hi);
  __syncthreads();
  stageA(As, ah, brow, nrows, t);
  stageB(Bs, Whz, t);
  __syncthreads();
  mfma16(As, Bs, accZ, wr, wc, lo, hi);

  const int c0 = wc*64;
  #pragma unroll
  for(int n=0;n<4;++n){
    const int colv = c0 + n*16 + lo;
    #pragma unroll
    for(int m=0;m<4;++m){
      int rbase = brow + wr*64 + m*16 + hi*4;
      #pragma unroll
      for(int tt=0;tt<4;++tt){
        int row = rbase + tt;
        if(row >= nrows) continue;
        Zb[(size_t)row*256 + colv]       = f2bf(accZ[m][n][tt]);
        Zb[(size_t)row*256 + 128 + colv] = f2bf(accH[m][n][tt]);
      }
    }
  }
}

// MODE 1: yq[row*128+col] = fp8( dinv*sigm(acc + b1+b2) * hl )
// MODE 2: z = sigm(bf2f(Zb[row*256+col]) + b1+b2);
//         ht = tanh(acc + bf2f(Zb[row*256+128+col]) + b3+b4)
//         outp = z*hl + (1-z)*ht;  optional y2out[row*256+col] = fp8(dinv*outp)
template<int MODE>
__global__ __launch_bounds__(256) void k_gemm(const unsigned short* __restrict__ A1,
    const unsigned short* __restrict__ A2, const unsigned short* __restrict__ B1,
    const unsigned short* __restrict__ B2, const unsigned short* __restrict__ Zb,
    const float* __restrict__ hl, const float* __restrict__ dinv,
    const float* __restrict__ b1, const float* __restrict__ b2,
    const float* __restrict__ b3, const float* __restrict__ b4,
    unsigned char* __restrict__ yq, float* __restrict__ outp,
    unsigned char* __restrict__ y2out, int nrows)
{
  __shared__ unsigned short As[128*136];
  __shared__ unsigned short Bs[128*136];
  const int t = threadIdx.x;
  const int lane = t & 63;
  const int lo = lane & 15, hi = lane >> 4;
  const int wid = t >> 6;
  const int wr = wid >> 1, wc = wid & 1;
  const int brow = blockIdx.x * 128;
  f4 acc[4][4];
  #pragma unroll
  for(int m=0;m<4;++m)
    #pragma unroll
    for(int n=0;n<4;++n) acc[m][n] = (f4)0.f;

  const int nch = A2 ? 2 : 1;
  for(int ch=0; ch<nch; ++ch){
    __syncthreads();
    stageA(As, ch ? A2 : A1, brow, nrows, t);
    stageB(Bs, ch ? B2 : B1, t);
    __syncthreads();
    mfma16(As, Bs, acc, wr, wc, lo, hi);
  }

  const int c0 = wc*64;
  #pragma unroll
  for(int n=0;n<4;++n){
    const int colv = c0 + n*16 + lo;
    float bz = b1[colv] + b2[colv];
    float bh = 0.f;
    if constexpr(MODE==2){ bh = b3[colv] + b4[colv]; }
    #pragma unroll
    for(int m=0;m<4;++m){
      int rbase = brow + wr*64 + m*16 + hi*4;
      #pragma unroll
      for(int tt=0;tt<4;++tt){
        int row = rbase + tt;
        if(row >= nrows) continue;
        float v = acc[m][n][tt];
        if constexpr(MODE==1){
          float r = sigm(v + bz);
          float q = dinv[row] * r * hl[(size_t)row*128 + colv];
          unsigned pk = __builtin_amdgcn_cvt_pk_fp8_f32(q, q, 0, false);
          yq[(size_t)row*128 + colv] = (unsigned char)(pk & 0xff);
        } else {
          float z  = sigm(bf2f(Zb[(size_t)row*256 + colv]) + bz);
          float ht = tanhf(v + bf2f(Zb[(size_t)row*256 + 128 + colv]) + bh);
          float ov = z*hl[(size_t)row*128 + colv] + (1.f - z)*ht;
          outp[(size_t)row*128 + colv] = ov;
          if(y2out){
            float q = dinv[row] * ov;
            unsigned pk = __builtin_amdgcn_cvt_pk_fp8_f32(q, q, 0, false);
            y2out[(size_t)row*256 + colv] = (unsigned char)(pk & 0xff);
          }
        }
      }
    }
  }
}

extern "C" void kernel_launch(void* const* d_in, const int* in_sizes, int n_in,
                              void* d_out, int out_size, void* d_ws, size_t ws_size,
                              hipStream_t stream){
  const float* x  = (const float*)d_in[0];
  const int*   ei = (const int*)d_in[1];
  const float* h  = (const float*)d_in[2];
  const float* Wx = (const float*)d_in[3];
  const float* bx = (const float*)d_in[4];
  const float* Wh = (const float*)d_in[5];
  const float* bh = (const float*)d_in[6];
  float* out = (float*)d_out;

  const int N = in_sizes[0] / 128;
  const int E = in_sizes[1] / 2;
  const int L = in_sizes[2] / in_sizes[0];
  const int* src = ei;
  const int* dst = ei + E;

  char* w = (char*)d_ws;
  auto alloc = [&](size_t b)->char*{ char* p = w; w += (b + 255) & ~(size_t)255; return p; };
  int* cnt = (int*)alloc((size_t)N*sizeof(int));
  unsigned short* col = (unsigned short*)alloc((size_t)N*CAP*sizeof(short));
  float* dinv = (float*)alloc((size_t)N*sizeof(float));
  unsigned short* WT = (unsigned short*)alloc((size_t)12*16384*sizeof(short));
  unsigned char* y2 = (unsigned char*)alloc((size_t)N*256);
  unsigned short* ax = (unsigned short*)alloc((size_t)N*128*sizeof(short));
  unsigned short* ah = (unsigned short*)alloc((size_t)N*128*sizeof(short));
  unsigned char* yq = (unsigned char*)alloc((size_t)N*128);
  unsigned short* aq = (unsigned short*)alloc((size_t)N*128*sizeof(short));
  unsigned short* Zb = (unsigned short*)alloc((size_t)N*256*sizeof(short));
  unsigned* ebuf = (unsigned*)alloc((size_t)NRG*NBB*SEGC*sizeof(unsigned));
  int* cnt2 = (int*)alloc((size_t)NRG*NBB*sizeof(int));

  const int gN = (N + 255)/256;
  const int gew = (N*32 + 255)/256;
  const int grows = (N + 127)/128;
  const int gagg4 = (N + 15)/16;   // DB=256: 16 nodes/block
  const int gagg2 = (N + 31)/32;   // DB=128: 32 nodes/block

  k_bucket<<<NBB,256,0,stream>>>(src, dst, ebuf, cnt2, E, N);
  k_build2<<<NRG,256,0,stream>>>(ebuf, cnt2, cnt, col, N);
  k_setup<<<gN + 768,256,0,stream>>>(cnt, dinv, N, Wx, Wh, WT);

  for(int l=0; l<L; ++l){
    const float* inp = (l==0) ? x : (out + (size_t)(l-1)*N*128);
    const float* hl  = h + (size_t)l*N*128;
    const float* bxz = bx + (size_t)(l*3+0)*128; const float* bhz = bh + (size_t)(l*3+0)*128;
    const float* bxr = bx + (size_t)(l*3+1)*128; const float* bhr = bh + (size_t)(l*3+1)*128;
    const float* bxh = bx + (size_t)(l*3+2)*128; const float* bhh = bh + (size_t)(l*3+2)*128;
    const unsigned short* Wxz = WT + (size_t)(l*3+0)*16384;
    const unsigned short* Wxr = WT + (size_t)(l*3+1)*16384;
    const unsigned short* Wxh = WT + (size_t)(l*3+2)*16384;
    const unsigned short* Whz = WT + (size_t)(6+l*3+0)*16384;
    const unsigned short* Whr = WT + (size_t)(6+l*3+1)*16384;
    const unsigned short* Whh = WT + (size_t)(6+l*3+2)*16384;

    if(l==0) k_scale2<1><<<gew,256,0,stream>>>(inp, hl, dinv, y2, N);
    else     k_scale2<0><<<gew,256,0,stream>>>(inp, hl, dinv, y2, N);
    k_agg<256><<<gagg4,256,0,stream>>>(y2, cnt, col, dinv, ax, ah, N);
    // fused z-pre + ht-partial
    k_gemmZH<<<grows,256,0,stream>>>(ax, ah, Wxz, Whz, Wxh, Zb, N);
    // r fused: yq = fp8(dinv * sigm(ax@Wxr + ah@Whr + bxr+bhr) * h)
    k_gemm<1><<<grows,256,0,stream>>>(ax, ah, Wxr, Whr, nullptr,
                                      hl, dinv, bxr, bhr, nullptr, nullptr,
                                      yq, nullptr, nullptr, N);
    k_agg<128><<<gagg2,256,0,stream>>>(yq, cnt, col, dinv, aq, nullptr, N);
    // final fused: out = z*h + (1-z)*tanh(aq@Whh + Zb[:,128:256] + bxh+bhh)
    // also emit next layer's y2 x-half = fp8(dinv*out)
    k_gemm<2><<<grows,256,0,stream>>>(aq, nullptr, Whh, nullptr, Zb,
                                      hl, dinv, bxz, bhz, bxh, bhh,
                                      nullptr, out + (size_t)l*N*128,
                                      (l+1<L) ? y2 : nullptr, N);
  }
}